// Round 2
// baseline (426.550 us; speedup 1.0000x reference)
//
#include <hip/hip_runtime.h>
#include <stdint.h>
#include <stddef.h>

// Problem constants
#define N_ROWS 131072
#define D_DIM  64
#define K_PROT 512
#define ND     (N_ROWS * D_DIM)                       // 8388608 elements per xn copy
#define PO     ((size_t)2 * (size_t)ND)               // proto_out offset (elements)
#define SO     (PO + (size_t)N_ROWS * (size_t)K_PROT) // scalars offset (elements)

typedef float          float4v  __attribute__((ext_vector_type(4)));
typedef short          short8v  __attribute__((ext_vector_type(8)));
typedef unsigned short ushort4v __attribute__((ext_vector_type(4)));

// fp32 -> bf16 RNE (internal MFMA dtype only; d_out itself is fp32)
__device__ __forceinline__ unsigned short f2bf(float f) {
    unsigned int u = __builtin_bit_cast(unsigned int, f);
    return (unsigned short)((u + 0x7FFFu + ((u >> 16) & 1u)) >> 16);
}

// ---------------- prep: re-init workspace accumulators (runs every launch) ----
__global__ void prep_kernel(unsigned int* __restrict__ colmin,
                            float* __restrict__ rowsum) {
    int k = threadIdx.x;          // 512 threads
    colmin[k] = 0x7F800000u;      // +inf bits
    if (k == 0) *rowsum = 0.0f;
}

// ---------------- main fused kernel ------------------------------------------
// grid 1024 x 512 threads. Block handles 128 rows (8 waves x 16 rows).
struct SMem {
    alignas(16) unsigned short wlds[K_PROT * D_DIM]; // 65536 B, swizzled bf16 W
    alignas(16) float w2[K_PROT];                    // 2048 B  (||W_k||^2 fp32)
    alignas(16) float xn2[8][16];                    // 512 B   per-wave row ||xn||^2
    alignas(16) unsigned int colmin[K_PROT];         // 2048 B  block col-min (sq bits)
    alignas(16) unsigned short atile[8][16 * D_DIM]; // 16384 B per-wave swizzled xn tile
    float rowsum;                                    // block sum of sqrt(rowmin)
};

__launch_bounds__(512, 2)
__global__ void main_kernel(const float* __restrict__ x,
                            const float* __restrict__ Wg,
                            unsigned int* __restrict__ colming,
                            float* __restrict__ rowsumg,
                            float* __restrict__ out) {
    __shared__ SMem s;
    const int tid  = threadIdx.x;
    const int wave = tid >> 6;
    const int L    = tid & 63;
    const int q    = L >> 4;   // 16-lane group (quad) 0..3
    const int l4   = L & 15;   // lane within group

    // ---- phase 0: init block LDS accumulators ----
    s.w2[tid]     = 0.0f;
    s.colmin[tid] = 0x7F800000u;
    if (tid == 0) s.rowsum = 0.0f;
    __syncthreads();

    // ---- phase 1a: stage W -> LDS bf16, swizzled; accumulate w2 in fp32 ----
    // W is 512x64 fp32 = 8192 float4. Chunk = 8 consecutive d (16 B bf16);
    // chunk c of row r stored at c' = c ^ (r&7)  => B-frag b128 reads conflict-free.
    {
        const float4v* Wv = (const float4v*)Wg;
        #pragma unroll
        for (int i = 0; i < 16; ++i) {
            int idx = tid + 512 * i;        // 0..8191
            float4v v = Wv[idx];
            int r    = idx >> 4;            // row 0..511
            int c    = (idx & 15) >> 1;     // chunk 0..7
            int half = idx & 1;             // low/high 8 B of the chunk
            int cp   = c ^ (r & 7);
            ushort4v p = { f2bf(v.x), f2bf(v.y), f2bf(v.z), f2bf(v.w) };
            *(ushort4v*)&s.wlds[r * 64 + cp * 8 + half * 4] = p;
            atomicAdd(&s.w2[r], v.x * v.x + v.y * v.y + v.z * v.z + v.w * v.w);
        }
    }

    // ---- phase 1b: load x tile, normalize, emit xn (fp32), build bf16 A-tile ----
    const int rowBase = (int)blockIdx.x * 128 + wave * 16;
    const float4v* xv = (const float4v*)(x + (size_t)rowBase * D_DIM);
    unsigned short* atile = s.atile[wave];

    #pragma unroll
    for (int j = 0; j < 4; ++j) {
        float4v v = xv[j * 64 + L];         // row j*4+q, elems l4*4..+3, coalesced 1 KB
        float ss = v.x * v.x + v.y * v.y + v.z * v.z + v.w * v.w;
        ss += __shfl_xor(ss, 1);
        ss += __shfl_xor(ss, 2);
        ss += __shfl_xor(ss, 4);
        ss += __shfl_xor(ss, 8);            // all 16 lanes of the group share row sum
        float nrm   = sqrtf(ss);
        float scale = 1.0f / fmaxf(nrm, 1e-12f);
        float4v xn  = v * scale;
        int row_l = j * 4 + q;
        int rowg  = rowBase + row_l;
        // fp32 outputs 0 and 1
        *(float4v*)&out[(size_t)rowg * D_DIM + l4 * 4]              = xn;
        *(float4v*)&out[(size_t)ND + (size_t)rowg * D_DIM + l4 * 4] = xn;
        // bf16 A-tile (swizzled like W): chunk c = l4>>1, half = l4&1
        ushort4v p = { f2bf(xn.x), f2bf(xn.y), f2bf(xn.z), f2bf(xn.w) };
        int cp = (l4 >> 1) ^ (row_l & 7);
        *(ushort4v*)&atile[row_l * 64 + cp * 8 + (l4 & 1) * 4] = p;
        if (l4 == 0) s.xn2[wave][row_l] = ss * scale * scale;
    }
    __syncthreads();   // W/w2 visible to all; A-tile/xn2 ordered (safety)

    // ---- phase 2: MFMA over 32 col-tiles + fused epilogue ----
    // A frag: A[m=l4][k=q*8+j (+32*kh)]  -> row l4, chunk kh*4+q of A-tile
    short8v afrag[2];
    #pragma unroll
    for (int kh = 0; kh < 2; ++kh) {
        int cp = (kh * 4 + q) ^ (l4 & 7);
        afrag[kh] = *(const short8v*)&atile[l4 * 64 + cp * 8];
    }
    float4v x2v = *(const float4v*)&s.xn2[wave][q * 4];  // rows q*4..q*4+3

    float rowmin[4] = { __builtin_inff(), __builtin_inff(),
                        __builtin_inff(), __builtin_inff() };
    float* outp = out + PO;

    for (int ct = 0; ct < 32; ++ct) {
        int rw = ct * 16 + l4;              // W row == global col for this lane
        float4v acc = { 0.f, 0.f, 0.f, 0.f };
        #pragma unroll
        for (int kh = 0; kh < 2; ++kh) {
            // B frag: B[k=q*8+j][n=l4] = W[col=rw][d=kh*32+q*8+j]
            int cp = (kh * 4 + q) ^ (l4 & 7);
            short8v bfrag = *(const short8v*)&s.wlds[rw * 64 + cp * 8];
            acc = __builtin_amdgcn_mfma_f32_16x16x32_bf16(afrag[kh], bfrag, acc, 0, 0, 0);
        }
        float w2c = s.w2[rw];
        float m4  = __builtin_inff();
        #pragma unroll
        for (int reg = 0; reg < 4; ++reg) {
            float dot = acc[reg];
            int rowg  = rowBase + q * 4 + reg;      // C/D: row=(quad)*4+reg, col=l4
            outp[(size_t)rowg * K_PROT + rw] = dot; // fp32 proto_out
            float sq = fmaxf(x2v[reg] + w2c - 2.0f * dot, 1e-12f);
            rowmin[reg] = fminf(rowmin[reg], sq);
            m4 = fminf(m4, sq);
        }
        // col-min across this wave's 16 rows (4 quads race via LDS atomic)
        atomicMin(&s.colmin[rw], __builtin_bit_cast(unsigned int, m4));
    }

    // ---- phase 3: row-min reduction (min over the 512 cols per row) ----
    #pragma unroll
    for (int m = 1; m <= 8; m <<= 1) {
        #pragma unroll
        for (int reg = 0; reg < 4; ++reg)
            rowmin[reg] = fminf(rowmin[reg], __shfl_xor(rowmin[reg], m));
    }
    float rs = 0.0f;
    if (l4 == 0) {
        #pragma unroll
        for (int reg = 0; reg < 4; ++reg) rs += sqrtf(rowmin[reg]);
    }
    rs += __shfl_xor(rs, 16);
    rs += __shfl_xor(rs, 32);
    if (L == 0) atomicAdd(&s.rowsum, rs);   // wave's 16 rows -> block sum
    __syncthreads();

    // ---- phase 4: flush block results to workspace ----
    atomicMin(&colming[tid], s.colmin[tid]);
    if (tid == 0) atomicAdd(rowsumg, s.rowsum);
}

// ---------------- final: scalars ---------------------------------------------
__global__ void final_kernel(const float* __restrict__ recon,
                             const float* __restrict__ kl,
                             const float* __restrict__ mmd,
                             const unsigned int* __restrict__ colmin,
                             const float* __restrict__ rowsum,
                             float* __restrict__ out) {
    __shared__ float wsum[8];
    int tid = threadIdx.x;   // 512 threads
    float v = sqrtf(__builtin_bit_cast(float, colmin[tid]));
    #pragma unroll
    for (int m = 1; m <= 32; m <<= 1) v += __shfl_xor(v, m);
    if ((tid & 63) == 0) wsum[tid >> 6] = v;
    __syncthreads();
    if (tid == 0) {
        float cs = 0.0f;
        #pragma unroll
        for (int i = 0; i < 8; ++i) cs += wsum[i];
        float prot = 0.5f * (rowsum[0] / (float)N_ROWS) + 0.5f * (cs / (float)K_PROT);
        float cvae = recon[0] + 0.5f * kl[0] + mmd[0];
        out[SO + 0] = cvae;
        out[SO + 1] = prot;
    }
}

extern "C" void kernel_launch(void* const* d_in, const int* in_sizes, int n_in,
                              void* d_out, int out_size, void* d_ws, size_t ws_size,
                              hipStream_t stream) {
    const float* x     = (const float*)d_in[0];
    const float* W     = (const float*)d_in[1];
    const float* recon = (const float*)d_in[2];
    const float* kl    = (const float*)d_in[3];
    const float* mmd   = (const float*)d_in[4];
    float* out = (float*)d_out;

    char* ws = (char*)d_ws;
    unsigned int* colmin = (unsigned int*)ws;            // 2048 B
    float*        rowsum = (float*)(ws + 2048);          // 4 B

    prep_kernel<<<1, 512, 0, stream>>>(colmin, rowsum);
    main_kernel<<<N_ROWS / 128, 512, 0, stream>>>(x, W, colmin, rowsum, out);
    final_kernel<<<1, 512, 0, stream>>>(recon, kl, mmd, colmin, rowsum, out);
}